// Round 1
// baseline (624.405 us; speedup 1.0000x reference)
//
#include <hip/hip_runtime.h>
#include <cstdint>
#include <cstddef>

// ---------------------------------------------------------------------------
// FFTFrequencyFilter: FFT highpass (== circular conv with per-channel 11x11
// kernel) -> 1x1 conv (GEMM, bf16 MFMA) -> BN -> ReLU -> gated residual.
// B=128, C=2048, H=W=11 (HW=121), N = B*HW = 15488.
// ---------------------------------------------------------------------------

#define C_DIM 2048
#define HW 121
#define NB 128
#define NTOT (NB * HW)  // 15488

__device__ __forceinline__ unsigned short f2bf(float f) {
  union { float f; unsigned int u; } v;
  v.f = f;
  unsigned int r = (v.u + 0x7FFFu + ((v.u >> 16) & 1u)) >> 16;
  return (unsigned short)r;
}

typedef __bf16 bfrag __attribute__((ext_vector_type(8)));
typedef float f32x4 __attribute__((ext_vector_type(4)));

__device__ __forceinline__ void gload_lds16(const void* g, void* l) {
  __builtin_amdgcn_global_load_lds(
      (const __attribute__((address_space(1))) unsigned int*)(uintptr_t)g,
      (__attribute__((address_space(3))) unsigned int*)(uintptr_t)l, 16, 0, 0);
}

// ---------------------------------------------------------------------------
// Pass 1: per-channel spatial kernel k_c[11][11] (row-padded to 16 floats),
// plus epilogue constants alpha/beta2. One block per channel.
// k[h][w] = (1/121) * sum_{u,v} Mu[u][v] * cos(2*pi*(u*h+v*w)/11),
// Mu[u][v] = mask_shifted[(u+5)%11][(v+5)%11].
// ---------------------------------------------------------------------------
__global__ __launch_bounds__(256) void prep_kernel(
    const float* __restrict__ ft, const float* __restrict__ convb,
    const float* __restrict__ gamma, const float* __restrict__ beta,
    const float* __restrict__ mean, const float* __restrict__ var,
    float* __restrict__ kws, float* __restrict__ alpha,
    float* __restrict__ beta2) {
  __shared__ float msk[121];
  __shared__ float ctab[11];
  const int c = blockIdx.x;
  const int t = threadIdx.x;
  float cutoff = ft[c];
  cutoff = fminf(fmaxf(cutoff, 0.05f), 0.5f);
  if (t < 121) {
    int h = t / 11, w = t - (t / 11) * 11;
    float dy = (float)(h - 5), dx = (float)(w - 5);
    float dn = sqrtf(dy * dy + dx * dx) / (sqrtf(50.0f) + 1e-6f);
    msk[t] = 1.0f / (1.0f + expf(-10.0f * (dn - cutoff)));
  }
  if (t < 11) ctab[t] = cosf(6.283185307179586f * (float)t / 11.0f);
  if (t == 128) {
    float inv = gamma[c] * rsqrtf(var[c] + 1e-5f);
    alpha[c] = inv;
    beta2[c] = (convb[c] - mean[c]) * inv + beta[c];
  }
  __syncthreads();
  if (t < 176) {  // 11 rows x 16 padded cols
    int h = t >> 4, w = t & 15;
    float val = 0.0f;
    if (w < 11) {
      float acc = 0.0f;
      for (int u = 0; u < 11; u++) {
        int us = u + 5; if (us >= 11) us -= 11;
        for (int v = 0; v < 11; v++) {
          int vs = v + 5; if (vs >= 11) vs -= 11;
          int r = (u * h + v * w) % 11;
          acc += msk[us * 11 + vs] * ctab[r];
        }
      }
      val = acc * (1.0f / 121.0f);
    }
    kws[(size_t)c * 176 + t] = val;
  }
}

// ---------------------------------------------------------------------------
// Pass 1b: conv_w fp32 -> bf16 (same [o][c] layout).
// ---------------------------------------------------------------------------
__global__ __launch_bounds__(256) void wconv_kernel(
    const float* __restrict__ W, unsigned short* __restrict__ Wb) {
  int idx = (blockIdx.x * 256 + threadIdx.x) * 8;
  float4 a = *(const float4*)(W + idx);
  float4 b = *(const float4*)(W + idx + 4);
  union { unsigned short s[8]; uint4 v; } u;
  u.s[0] = f2bf(a.x); u.s[1] = f2bf(a.y); u.s[2] = f2bf(a.z); u.s[3] = f2bf(a.w);
  u.s[4] = f2bf(b.x); u.s[5] = f2bf(b.y); u.s[6] = f2bf(b.z); u.s[7] = f2bf(b.w);
  *(uint4*)(Wb + idx) = u.v;
}

// ---------------------------------------------------------------------------
// Pass 2: circular conv filter. Block = (batch b, 64 channels), 704 threads.
// Thread t: plane = t/11 (channel), ph = t%11 (output row). x plane staged in
// LDS (rows padded to 16 floats for aligned float4 reads); k rows read from
// global (L2-resident, ~1.4MB total, reused by 128 b-blocks). Output written
// via LDS transpose into xf[n][c] bf16 (the GEMM's B^T layout).
// ---------------------------------------------------------------------------
__global__ __launch_bounds__(704) void filter_kernel(
    const float* __restrict__ x, const float* __restrict__ kws,
    unsigned short* __restrict__ xf) {
  __shared__ __align__(16) float lx[64 * 176];  // 45056 B, reused as out tile
  const int b = blockIdx.x;
  const int c0 = blockIdx.y * 64;
  const int tid = threadIdx.x;

  // stage x: 64 planes * 121 floats = 7744 = 704 * 11, coalesced
  const float* xsrc = x + ((size_t)b * C_DIM + c0) * HW;
#pragma unroll
  for (int i = 0; i < 11; i++) {
    int g = tid + i * 704;
    int pl = g / 121;
    int r = g - pl * 121;
    int rh = r / 11;
    int rw = r - rh * 11;
    lx[pl * 176 + rh * 16 + rw] = xsrc[g];
  }
  __syncthreads();

  const int pl = tid / 11;
  const int ph = tid - pl * 11;
  const float* xp = &lx[pl * 176];
  const float* kp = kws + (size_t)(c0 + pl) * 176;

  float acc[11];
#pragma unroll
  for (int w = 0; w < 11; w++) acc[w] = 0.0f;

  for (int kh = 0; kh < 11; kh++) {
    int qh = ph - kh; if (qh < 0) qh += 11;
    float4 xv0 = *(const float4*)(xp + qh * 16);
    float4 xv1 = *(const float4*)(xp + qh * 16 + 4);
    float4 xv2 = *(const float4*)(xp + qh * 16 + 8);
    float4 kv0 = *(const float4*)(kp + kh * 16);
    float4 kv1 = *(const float4*)(kp + kh * 16 + 4);
    float4 kv2 = *(const float4*)(kp + kh * 16 + 8);
    const float xr[12] = {xv0.x, xv0.y, xv0.z, xv0.w, xv1.x, xv1.y,
                          xv1.z, xv1.w, xv2.x, xv2.y, xv2.z, xv2.w};
    const float kr[12] = {kv0.x, kv0.y, kv0.z, kv0.w, kv1.x, kv1.y,
                          kv1.z, kv1.w, kv2.x, kv2.y, kv2.z, kv2.w};
#pragma unroll
    for (int qw = 0; qw < 11; qw++) {
      float xv = xr[qw];
#pragma unroll
      for (int pw = 0; pw < 11; pw++) {
        int ki = pw - qw; if (ki < 0) ki += 11;  // compile-time
        acc[pw] = fmaf(xv, kr[ki], acc[pw]);
      }
    }
  }
  __syncthreads();  // all x reads done; reuse lx as bf16 out tile [p][64 ch]

  unsigned short* lo = (unsigned short*)lx;
#pragma unroll
  for (int pw = 0; pw < 11; pw++)
    lo[(ph * 11 + pw) * 64 + pl] = f2bf(acc[pw]);
  __syncthreads();

  // cooperative coalesced write: 121 rows x 64 bf16 = 3872 dwords
  const unsigned int* lou = (const unsigned int*)lo;
#pragma unroll
  for (int i = 0; i < 6; i++) {
    int idx = tid + i * 704;
    if (idx < 3872) {
      int p = idx >> 5;
      int j = idx & 31;
      ((unsigned int*)(xf + (size_t)(b * HW + p) * C_DIM + c0))[j] = lou[idx];
    }
  }
}

// ---------------------------------------------------------------------------
// Pass 3: GEMM D[o][n] = sum_c Wb[o][c] * xf[n][c]  (m97 gemm_bt structure)
// BM=BN=128, BK=32, 256 thr, global_load_lds(16B), mfma_f32_16x16x32_bf16.
// Epilogue: out[b][o][p] = x[b][o][p] + g*relu(acc*alpha[o] + beta2[o]).
// ---------------------------------------------------------------------------
__global__ __launch_bounds__(256) void gemm_kernel(
    const unsigned short* __restrict__ Wb, const unsigned short* __restrict__ xf,
    const float* __restrict__ xres, const float* __restrict__ alpha,
    const float* __restrict__ beta2, const float* __restrict__ gate,
    float* __restrict__ out) {
  __shared__ __align__(16) unsigned short lds[8192];  // A:[0,4096) B:[4096,8192) shorts
  const int tid = threadIdx.x;
  const int wid = tid >> 6;
  const int lane = tid & 63;
  const int m0 = blockIdx.y << 7;
  const int n0 = blockIdx.x << 7;
  const int wm = (wid >> 1) << 6;
  const int wn = (wid & 1) << 6;

  f32x4 acc[4][4];
#pragma unroll
  for (int i = 0; i < 4; i++)
#pragma unroll
    for (int j = 0; j < 4; j++) acc[i][j] = f32x4{0.f, 0.f, 0.f, 0.f};

  // staging: 16 chunks of 1KB (8 A + 8 B); wave w takes A{w,w+4}, B{w,w+4}
  const int rowlo = (wid << 4) + (lane >> 2);
  const int seg = lane & 3;
  const unsigned short* gA0 = Wb + (size_t)(m0 + rowlo) * C_DIM + seg * 8;
  const unsigned short* gA1 = gA0 + 64 * C_DIM;
  const unsigned short* gB0 = xf + (size_t)(n0 + rowlo) * C_DIM + seg * 8;
  const unsigned short* gB1 = gB0 + 64 * C_DIM;
  char* lA0 = (char*)lds + (wid << 10) + (lane << 4);
  char* lA1 = lA0 + 4096;
  char* lB0 = lA0 + 8192;
  char* lB1 = lA0 + 12288;

  const int fr = lane & 15;
  const int quad = lane >> 4;
  const unsigned short* pa = lds + ((wm + fr) << 5) + (quad << 3);
  const unsigned short* pb = lds + 4096 + ((wn + fr) << 5) + (quad << 3);

  for (int kk = 0; kk < 64; kk++) {
    gload_lds16(gA0, lA0);
    gload_lds16(gA1, lA1);
    gload_lds16(gB0, lB0);
    gload_lds16(gB1, lB1);
    gA0 += 32; gA1 += 32; gB0 += 32; gB1 += 32;
    asm volatile("s_waitcnt vmcnt(0)" ::: "memory");
    __syncthreads();
    bfrag a[4], b[4];
#pragma unroll
    for (int i = 0; i < 4; i++) {
      a[i] = *(const bfrag*)(pa + (i << 9));
      b[i] = *(const bfrag*)(pb + (i << 9));
    }
#pragma unroll
    for (int i = 0; i < 4; i++)
#pragma unroll
      for (int j = 0; j < 4; j++)
        acc[i][j] = __builtin_amdgcn_mfma_f32_16x16x32_bf16(a[i], b[j], acc[i][j], 0, 0, 0);
    __syncthreads();
  }

  // epilogue
  float g = gate[0];
  g = fminf(fmaxf(g, 0.0f), 1.0f);
  int nbase[4];
#pragma unroll
  for (int j = 0; j < 4; j++) {
    int n = n0 + wn + (j << 4) + fr;
    int bb = n / 121;
    int p = n - bb * 121;
    nbase[j] = bb * (C_DIM * HW) + p;
  }
#pragma unroll
  for (int i = 0; i < 4; i++) {
    const int ob = m0 + wm + (i << 4) + (quad << 2);
    float al[4], bt[4];
#pragma unroll
    for (int r = 0; r < 4; r++) { al[r] = alpha[ob + r]; bt[r] = beta2[ob + r]; }
#pragma unroll
    for (int j = 0; j < 4; j++) {
#pragma unroll
      for (int r = 0; r < 4; r++) {
        int addr = nbase[j] + (ob + r) * HW;
        float v = acc[i][j][r] * al[r] + bt[r];
        v = fmaxf(v, 0.0f);
        out[addr] = xres[addr] + g * v;
      }
    }
  }
}

// ---------------------------------------------------------------------------
// Workspace layout (needs ~76 MB):
//   [0x000000, +1441792)  kws: 2048 x 176 fp32 spatial kernels (row pad 16)
//   [0x200000, +8192)     alpha
//   [0x202000, +8192)     beta2
//   [0x300000, +8388608)  Wb bf16 [2048][2048]
//   [0xC00000, +63438848) xf bf16 [15488][2048]
// ---------------------------------------------------------------------------
extern "C" void kernel_launch(void* const* d_in, const int* in_sizes, int n_in,
                              void* d_out, int out_size, void* d_ws, size_t ws_size,
                              hipStream_t stream) {
  const float* x     = (const float*)d_in[0];
  const float* ft    = (const float*)d_in[1];
  const float* gate  = (const float*)d_in[2];
  const float* W     = (const float*)d_in[3];
  const float* convb = (const float*)d_in[4];
  const float* gamma = (const float*)d_in[5];
  const float* beta  = (const float*)d_in[6];
  const float* mean  = (const float*)d_in[7];
  const float* var   = (const float*)d_in[8];
  float* out = (float*)d_out;

  char* ws = (char*)d_ws;
  float* kws            = (float*)(ws);
  float* alpha          = (float*)(ws + 0x200000);
  float* beta2          = (float*)(ws + 0x202000);
  unsigned short* Wb    = (unsigned short*)(ws + 0x300000);
  unsigned short* xf    = (unsigned short*)(ws + 0xC00000);

  prep_kernel<<<2048, 256, 0, stream>>>(ft, convb, gamma, beta, mean, var,
                                        kws, alpha, beta2);
  wconv_kernel<<<2048, 256, 0, stream>>>(W, Wb);
  filter_kernel<<<dim3(NB, C_DIM / 64), 704, 0, stream>>>(x, kws, xf);
  gemm_kernel<<<dim3(NTOT / 128, C_DIM / 128), 256, 0, stream>>>(
      Wb, xf, x, alpha, beta2, gate, out);
}

// Round 3
// 535.343 us; speedup vs baseline: 1.1664x; 1.1664x over previous
//
#include <hip/hip_runtime.h>
#include <cstdint>
#include <cstddef>

// ---------------------------------------------------------------------------
// FFTFrequencyFilter: FFT highpass (== circular conv with per-channel 11x11
// kernel) -> 1x1 conv (GEMM, bf16 MFMA) -> BN -> ReLU -> gated residual.
// B=128, C=2048, H=W=11 (HW=121), N = B*HW = 15488.
// R3: R2 + fix pb to use wn (R2 bug: pb = pa + 8192 inherited wm -> waves
//     with wm!=wn read wrong B rows).
// ---------------------------------------------------------------------------

#define C_DIM 2048
#define HW 121
#define NB 128
#define NTOT (NB * HW)  // 15488

__device__ __forceinline__ unsigned short f2bf(float f) {
  union { float f; unsigned int u; } v;
  v.f = f;
  unsigned int r = (v.u + 0x7FFFu + ((v.u >> 16) & 1u)) >> 16;
  return (unsigned short)r;
}

typedef __bf16 bfrag __attribute__((ext_vector_type(8)));
typedef float f32x4 __attribute__((ext_vector_type(4)));
typedef float f32x2 __attribute__((ext_vector_type(2)));

__device__ __forceinline__ void gload_lds16(const void* g, void* l) {
  __builtin_amdgcn_global_load_lds(
      (const __attribute__((address_space(1))) unsigned int*)(uintptr_t)g,
      (__attribute__((address_space(3))) unsigned int*)(uintptr_t)l, 16, 0, 0);
}

// ---------------------------------------------------------------------------
// Pass 1: per-channel spatial kernel k_c[11][11] (row-padded to 16 floats),
// plus epilogue constants alpha/beta2. One block per channel.
// ---------------------------------------------------------------------------
__global__ __launch_bounds__(256) void prep_kernel(
    const float* __restrict__ ft, const float* __restrict__ convb,
    const float* __restrict__ gamma, const float* __restrict__ beta,
    const float* __restrict__ mean, const float* __restrict__ var,
    float* __restrict__ kws, float* __restrict__ alpha,
    float* __restrict__ beta2) {
  __shared__ float msk[121];
  __shared__ float ctab[11];
  const int c = blockIdx.x;
  const int t = threadIdx.x;
  float cutoff = ft[c];
  cutoff = fminf(fmaxf(cutoff, 0.05f), 0.5f);
  if (t < 121) {
    int h = t / 11, w = t - (t / 11) * 11;
    float dy = (float)(h - 5), dx = (float)(w - 5);
    float dn = sqrtf(dy * dy + dx * dx) / (sqrtf(50.0f) + 1e-6f);
    msk[t] = 1.0f / (1.0f + expf(-10.0f * (dn - cutoff)));
  }
  if (t < 11) ctab[t] = cosf(6.283185307179586f * (float)t / 11.0f);
  if (t == 128) {
    float inv = gamma[c] * rsqrtf(var[c] + 1e-5f);
    alpha[c] = inv;
    beta2[c] = (convb[c] - mean[c]) * inv + beta[c];
  }
  __syncthreads();
  if (t < 176) {  // 11 rows x 16 padded cols
    int h = t >> 4, w = t & 15;
    float val = 0.0f;
    if (w < 11) {
      float acc = 0.0f;
      int ru = 0;  // (u*h) % 11 incrementally
      int us = 5;
      for (int u = 0; u < 11; u++) {
        int rv = ru;  // (u*h + v*w) % 11 incrementally
        int vs = 5;
        for (int v = 0; v < 11; v++) {
          acc += msk[us * 11 + vs] * ctab[rv];
          rv += w; if (rv >= 11) rv -= 11;
          vs++; if (vs >= 11) vs -= 11;
        }
        ru += h; if (ru >= 11) ru -= 11;
        us++; if (us >= 11) us -= 11;
      }
      val = acc * (1.0f / 121.0f);
    }
    kws[(size_t)c * 176 + t] = val;
  }
}

// ---------------------------------------------------------------------------
// Pass 1b: conv_w fp32 -> bf16 (same [o][c] layout).
// ---------------------------------------------------------------------------
__global__ __launch_bounds__(256) void wconv_kernel(
    const float* __restrict__ W, unsigned short* __restrict__ Wb) {
  int idx = (blockIdx.x * 256 + threadIdx.x) * 8;
  float4 a = *(const float4*)(W + idx);
  float4 b = *(const float4*)(W + idx + 4);
  union { unsigned short s[8]; uint4 v; } u;
  u.s[0] = f2bf(a.x); u.s[1] = f2bf(a.y); u.s[2] = f2bf(a.z); u.s[3] = f2bf(a.w);
  u.s[4] = f2bf(b.x); u.s[5] = f2bf(b.y); u.s[6] = f2bf(b.z); u.s[7] = f2bf(b.w);
  *(uint4*)(Wb + idx) = u.v;
}

// ---------------------------------------------------------------------------
// Pass 2: circular conv filter. Block = (batch b, 64 channels), 704 threads.
// LDS x rows at stride 12 floats (48B, 16B-aligned, gcd(12,32)=4 -> 8 bank
// phases). Inner product as f32x2 packed FMA; kr[11]=kr[0] handles wrap.
// ---------------------------------------------------------------------------
#define XROW 12
#define XPL 132
__global__ __launch_bounds__(704) void filter_kernel(
    const float* __restrict__ x, const float* __restrict__ kws,
    unsigned short* __restrict__ xf) {
  __shared__ __align__(16) float lx[64 * XPL];  // 33792 B, reused as out tile
  const int b = blockIdx.x;
  const int c0 = blockIdx.y * 64;
  const int tid = threadIdx.x;

  const float* xsrc = x + ((size_t)b * C_DIM + c0) * HW;
#pragma unroll
  for (int i = 0; i < 11; i++) {
    int g = tid + i * 704;
    int pl = g / 121;
    int r = g - pl * 121;
    int rh = r / 11;
    int rw = r - rh * 11;
    lx[pl * XPL + rh * XROW + rw] = xsrc[g];
  }
  __syncthreads();

  const int pl = tid / 11;
  const int ph = tid - pl * 11;
  const float* xp = &lx[pl * XPL];
  const float* kp = kws + (size_t)(c0 + pl) * 176;

  f32x2 acc2[6];
#pragma unroll
  for (int i = 0; i < 6; i++) acc2[i] = f32x2{0.f, 0.f};

  for (int kh = 0; kh < 11; kh++) {
    int qh = ph - kh; if (qh < 0) qh += 11;
    f32x4 xv0 = *(const f32x4*)(xp + qh * XROW);
    f32x4 xv1 = *(const f32x4*)(xp + qh * XROW + 4);
    f32x4 xv2 = *(const f32x4*)(xp + qh * XROW + 8);
    f32x4 kv0 = *(const f32x4*)(kp + kh * 16);
    f32x4 kv1 = *(const f32x4*)(kp + kh * 16 + 4);
    f32x4 kv2 = *(const f32x4*)(kp + kh * 16 + 8);
    const float xr[11] = {xv0[0], xv0[1], xv0[2], xv0[3], xv1[0], xv1[1],
                          xv1[2], xv1[3], xv2[0], xv2[1], xv2[2]};
    float kr[12];
    kr[0] = kv0[0]; kr[1] = kv0[1]; kr[2] = kv0[2]; kr[3] = kv0[3];
    kr[4] = kv1[0]; kr[5] = kv1[1]; kr[6] = kv1[2]; kr[7] = kv1[3];
    kr[8] = kv2[0]; kr[9] = kv2[1]; kr[10] = kv2[2];
    kr[11] = kr[0];  // mod-11 wrap for the packed pair
#pragma unroll
    for (int qw = 0; qw < 11; qw++) {
      f32x2 xv = {xr[qw], xr[qw]};
#pragma unroll
      for (int p2 = 0; p2 < 6; p2++) {
        int ki = 2 * p2 - qw; if (ki < 0) ki += 11;  // compile-time
        f32x2 kpair = {kr[ki], kr[ki + 1]};
        acc2[p2] = xv * kpair + acc2[p2];
      }
    }
  }
  __syncthreads();  // reuse lx as bf16 out tile [p][64 ch]

  float accv[11];
#pragma unroll
  for (int p2 = 0; p2 < 6; p2++) {
    accv[2 * p2] = acc2[p2][0];
    if (2 * p2 + 1 < 11) accv[2 * p2 + 1] = acc2[p2][1];
  }

  unsigned short* lo = (unsigned short*)lx;
#pragma unroll
  for (int pw = 0; pw < 11; pw++)
    lo[(ph * 11 + pw) * 64 + pl] = f2bf(accv[pw]);
  __syncthreads();

  const unsigned int* lou = (const unsigned int*)lo;
#pragma unroll
  for (int i = 0; i < 6; i++) {
    int idx = tid + i * 704;
    if (idx < 3872) {
      int p = idx >> 5;
      int j = idx & 31;
      ((unsigned int*)(xf + (size_t)(b * HW + p) * C_DIM + c0))[j] = lou[idx];
    }
  }
}

// ---------------------------------------------------------------------------
// Pass 3: GEMM D[o][n] = sum_c Wb[o][c] * xf[n][c]
// BM=BN=128, BK=64 (two 32-wide half-tiles), 256 thr, global_load_lds(16B),
// mfma_f32_16x16x32_bf16, 32 barrier iters. L2 swizzle: 11 groups of
// (16 m-tiles x 11 n-tiles). LDS bytes: A h0 [0,8192) A h1 [8192,16384)
// B h0 [16384,24576) B h1 [24576,32768); rows of 64 B.
// Epilogue: out[b][o][p] = x[b][o][p] + g*relu(acc*alpha[o] + beta2[o]).
// ---------------------------------------------------------------------------
__global__ __launch_bounds__(256) void gemm_kernel(
    const unsigned short* __restrict__ Wb, const unsigned short* __restrict__ xf,
    const float* __restrict__ xres, const float* __restrict__ alpha,
    const float* __restrict__ beta2, const float* __restrict__ gate,
    float* __restrict__ out) {
  __shared__ __align__(16) unsigned short lds[16384];
  const int tid = threadIdx.x;
  const int wid = tid >> 6;
  const int lane = tid & 63;

  const int lid = blockIdx.y * 121 + blockIdx.x;
  const int grp = lid / 176;
  const int rem = lid - grp * 176;
  const int m0 = (rem & 15) << 7;
  const int n0 = (grp * 11 + (rem >> 4)) << 7;

  const int wm = (wid >> 1) << 6;
  const int wn = (wid & 1) << 6;

  f32x4 acc[4][4];
#pragma unroll
  for (int i = 0; i < 4; i++)
#pragma unroll
    for (int j = 0; j < 4; j++) acc[i][j] = f32x4{0.f, 0.f, 0.f, 0.f};

  const int rowlo = (wid << 4) + (lane >> 2);
  const int seg = lane & 3;
  const unsigned short* gA0 = Wb + (size_t)(m0 + rowlo) * C_DIM + seg * 8;
  const unsigned short* gA1 = gA0 + 64 * C_DIM;
  const unsigned short* gB0 = xf + (size_t)(n0 + rowlo) * C_DIM + seg * 8;
  const unsigned short* gB1 = gB0 + 64 * C_DIM;
  char* lA0 = (char*)lds + (wid << 10) + (lane << 4);
  char* lA1 = lA0 + 4096;

  const int fr = lane & 15;
  const int quad = lane >> 4;
  const unsigned short* pa = lds + ((wm + fr) << 5) + (quad << 3);
  const unsigned short* pb = lds + 8192 + ((wn + fr) << 5) + (quad << 3);  // R3 fix: wn

  for (int kk = 0; kk < 32; kk++) {
    gload_lds16(gA0,       lA0);
    gload_lds16(gA1,       lA1);
    gload_lds16(gA0 + 32,  lA0 + 8192);
    gload_lds16(gA1 + 32,  lA1 + 8192);
    gload_lds16(gB0,       lA0 + 16384);
    gload_lds16(gB1,       lA1 + 16384);
    gload_lds16(gB0 + 32,  lA0 + 24576);
    gload_lds16(gB1 + 32,  lA1 + 24576);
    gA0 += 64; gA1 += 64; gB0 += 64; gB1 += 64;
    asm volatile("s_waitcnt vmcnt(0)" ::: "memory");
    __syncthreads();
#pragma unroll
    for (int ks = 0; ks < 2; ks++) {
      bfrag a[4], b[4];
#pragma unroll
      for (int i = 0; i < 4; i++) {
        a[i] = *(const bfrag*)(pa + (ks << 12) + (i << 9));
        b[i] = *(const bfrag*)(pb + (ks << 12) + (i << 9));
      }
#pragma unroll
      for (int i = 0; i < 4; i++)
#pragma unroll
        for (int j = 0; j < 4; j++)
          acc[i][j] = __builtin_amdgcn_mfma_f32_16x16x32_bf16(a[i], b[j], acc[i][j], 0, 0, 0);
    }
    __syncthreads();
  }

  // epilogue
  float g = gate[0];
  g = fminf(fmaxf(g, 0.0f), 1.0f);
  int nbase[4];
#pragma unroll
  for (int j = 0; j < 4; j++) {
    int n = n0 + wn + (j << 4) + fr;
    int bb = n / 121;
    int p = n - bb * 121;
    nbase[j] = bb * (C_DIM * HW) + p;
  }
#pragma unroll
  for (int i = 0; i < 4; i++) {
    const int ob = m0 + wm + (i << 4) + (quad << 2);
    float al[4], bt[4];
#pragma unroll
    for (int r = 0; r < 4; r++) { al[r] = alpha[ob + r]; bt[r] = beta2[ob + r]; }
#pragma unroll
    for (int j = 0; j < 4; j++) {
#pragma unroll
      for (int r = 0; r < 4; r++) {
        int addr = nbase[j] + (ob + r) * HW;
        float v = acc[i][j][r] * al[r] + bt[r];
        v = fmaxf(v, 0.0f);
        out[addr] = xres[addr] + g * v;
      }
    }
  }
}

// ---------------------------------------------------------------------------
// Workspace layout (needs ~76 MB):
//   [0x000000, +1441792)  kws: 2048 x 176 fp32 spatial kernels (row pad 16)
//   [0x200000, +8192)     alpha
//   [0x202000, +8192)     beta2
//   [0x300000, +8388608)  Wb bf16 [2048][2048]
//   [0xC00000, +63438848) xf bf16 [15488][2048]
// ---------------------------------------------------------------------------
extern "C" void kernel_launch(void* const* d_in, const int* in_sizes, int n_in,
                              void* d_out, int out_size, void* d_ws, size_t ws_size,
                              hipStream_t stream) {
  const float* x     = (const float*)d_in[0];
  const float* ft    = (const float*)d_in[1];
  const float* gate  = (const float*)d_in[2];
  const float* W     = (const float*)d_in[3];
  const float* convb = (const float*)d_in[4];
  const float* gamma = (const float*)d_in[5];
  const float* beta  = (const float*)d_in[6];
  const float* mean  = (const float*)d_in[7];
  const float* var   = (const float*)d_in[8];
  float* out = (float*)d_out;

  char* ws = (char*)d_ws;
  float* kws            = (float*)(ws);
  float* alpha          = (float*)(ws + 0x200000);
  float* beta2          = (float*)(ws + 0x202000);
  unsigned short* Wb    = (unsigned short*)(ws + 0x300000);
  unsigned short* xf    = (unsigned short*)(ws + 0xC00000);

  prep_kernel<<<2048, 256, 0, stream>>>(ft, convb, gamma, beta, mean, var,
                                        kws, alpha, beta2);
  wconv_kernel<<<2048, 256, 0, stream>>>(W, Wb);
  filter_kernel<<<dim3(NB, C_DIM / 64), 704, 0, stream>>>(x, kws, xf);
  gemm_kernel<<<dim3(NTOT / 128, C_DIM / 128), 256, 0, stream>>>(
      Wb, xf, x, alpha, beta2, gate, out);
}

// Round 4
// 468.472 us; speedup vs baseline: 1.3329x; 1.1427x over previous
//
#include <hip/hip_runtime.h>
#include <cstdint>
#include <cstddef>

// ---------------------------------------------------------------------------
// FFTFrequencyFilter: FFT highpass (== circular conv with per-channel 11x11
// kernel) -> 1x1 conv (GEMM, bf16 MFMA) -> BN -> ReLU -> gated residual.
// B=128, C=2048, H=W=11 (HW=121), N = B*HW = 15488.
// R4: filter rewritten with kh-symmetry (k even in h,w mod 11 => 726 FMA +
//     55 adds, all scalar), 384-thr/32-ch blocks (30 waves/CU vs 22);
//     wconv merged into prep. GEMM identical to R3.
// ---------------------------------------------------------------------------

#define C_DIM 2048
#define HW 121
#define NB 128
#define NTOT (NB * HW)  // 15488

__device__ __forceinline__ unsigned short f2bf(float f) {
  union { float f; unsigned int u; } v;
  v.f = f;
  unsigned int r = (v.u + 0x7FFFu + ((v.u >> 16) & 1u)) >> 16;
  return (unsigned short)r;
}

typedef __bf16 bfrag __attribute__((ext_vector_type(8)));
typedef float f32x4 __attribute__((ext_vector_type(4)));

__device__ __forceinline__ void gload_lds16(const void* g, void* l) {
  __builtin_amdgcn_global_load_lds(
      (const __attribute__((address_space(1))) unsigned int*)(uintptr_t)g,
      (__attribute__((address_space(3))) unsigned int*)(uintptr_t)l, 16, 0, 0);
}

// ---------------------------------------------------------------------------
// Pass 1: per-channel spatial kernel k_c[11][11] (row-padded to 16 floats),
// epilogue constants alpha/beta2, AND W fp32->bf16 (row c per block).
// ---------------------------------------------------------------------------
__global__ __launch_bounds__(256) void prep_kernel(
    const float* __restrict__ ft, const float* __restrict__ convb,
    const float* __restrict__ gamma, const float* __restrict__ beta,
    const float* __restrict__ mean, const float* __restrict__ var,
    const float* __restrict__ W, unsigned short* __restrict__ Wb,
    float* __restrict__ kws, float* __restrict__ alpha,
    float* __restrict__ beta2) {
  __shared__ float msk[121];
  __shared__ float ctab[11];
  const int c = blockIdx.x;
  const int t = threadIdx.x;

  // W row c -> bf16 (8 elements/thread, coalesced)
  {
    int base = c * C_DIM + t * 8;
    float4 a = *(const float4*)(W + base);
    float4 b = *(const float4*)(W + base + 4);
    union { unsigned short s[8]; uint4 v; } u;
    u.s[0] = f2bf(a.x); u.s[1] = f2bf(a.y); u.s[2] = f2bf(a.z); u.s[3] = f2bf(a.w);
    u.s[4] = f2bf(b.x); u.s[5] = f2bf(b.y); u.s[6] = f2bf(b.z); u.s[7] = f2bf(b.w);
    *(uint4*)(Wb + base) = u.v;
  }

  float cutoff = ft[c];
  cutoff = fminf(fmaxf(cutoff, 0.05f), 0.5f);
  if (t < 121) {
    int h = t / 11, w = t - (t / 11) * 11;
    float dy = (float)(h - 5), dx = (float)(w - 5);
    float dn = sqrtf(dy * dy + dx * dx) / (sqrtf(50.0f) + 1e-6f);
    msk[t] = 1.0f / (1.0f + expf(-10.0f * (dn - cutoff)));
  }
  if (t < 11) ctab[t] = cosf(6.283185307179586f * (float)t / 11.0f);
  if (t == 128) {
    float inv = gamma[c] * rsqrtf(var[c] + 1e-5f);
    alpha[c] = inv;
    beta2[c] = (convb[c] - mean[c]) * inv + beta[c];
  }
  __syncthreads();
  if (t < 176) {  // 11 rows x 16 padded cols
    int h = t >> 4, w = t & 15;
    float val = 0.0f;
    if (w < 11) {
      float acc = 0.0f;
      int ru = 0;
      int us = 5;
      for (int u = 0; u < 11; u++) {
        int rv = ru;
        int vs = 5;
        for (int v = 0; v < 11; v++) {
          acc += msk[us * 11 + vs] * ctab[rv];
          rv += w; if (rv >= 11) rv -= 11;
          vs++; if (vs >= 11) vs -= 11;
        }
        ru += h; if (ru >= 11) ru -= 11;
        us++; if (us >= 11) us -= 11;
      }
      val = acc * (1.0f / 121.0f);
    }
    kws[(size_t)c * 176 + t] = val;
  }
}

// ---------------------------------------------------------------------------
// Pass 2: circular conv filter using k's h-symmetry.
// k[(11-d)%11][w] == k[d][w] (radial mask => Mu even in u,v mod 11), so
//   out[ph] = sum_{d=0..5} circ_conv_1d(k[d], R_d),
//   R_d[qw] = X[(ph-d)%11][qw] + X[(ph+d)%11][qw]   (R_0 = X[ph]).
// Block = (batch, 32 channels), 384 threads (352 compute: pl=t/11, ph=t%11).
// LDS: x rows stride 12 (8 bank phases); separate bf16 out tile [p][32ch].
// ---------------------------------------------------------------------------
#define XROW 12
#define XPL 132
#define FC 32
__global__ __launch_bounds__(384) void filter_kernel(
    const float* __restrict__ x, const float* __restrict__ kws,
    unsigned short* __restrict__ xf) {
  __shared__ __align__(16) float lx[FC * XPL];          // 16896 B
  __shared__ __align__(16) unsigned short lo[HW * FC];  // 7744 B
  const int b = blockIdx.x;
  const int c0 = blockIdx.y * FC;
  const int tid = threadIdx.x;

  // stage 32 planes = 3872 contiguous floats = 968 float4 (16B-aligned)
  const float* xsrc = x + ((size_t)b * C_DIM + c0) * HW;
#pragma unroll
  for (int i = 0; i < 3; i++) {
    int v = tid + i * 384;
    if (v < 968) {
      float4 xv = *(const float4*)(xsrc + v * 4);
      int g = v * 4;
#pragma unroll
      for (int e = 0; e < 4; e++) {
        int ge = g + e;
        int pl = ge / 121;
        int r = ge - pl * 121;
        int rh = r / 11;
        int rw = r - rh * 11;
        lx[pl * XPL + rh * XROW + rw] = (&xv.x)[e];
      }
    }
  }
  __syncthreads();

  if (tid < 352) {
    const int pl = tid / 11;
    const int ph = tid - pl * 11;
    const float* xp = &lx[pl * XPL];
    const float* kp = kws + (size_t)(c0 + pl) * 176;

    float accv[11];
#pragma unroll
    for (int i = 0; i < 11; i++) accv[i] = 0.f;

#pragma unroll
    for (int d = 0; d <= 5; d++) {
      int q0 = ph - d; if (q0 < 0) q0 += 11;
      f32x4 r0 = *(const f32x4*)(xp + q0 * XROW);
      f32x4 r1 = *(const f32x4*)(xp + q0 * XROW + 4);
      f32x4 r2 = *(const f32x4*)(xp + q0 * XROW + 8);
      if (d > 0) {
        int q1 = ph + d; if (q1 >= 11) q1 -= 11;
        r0 += *(const f32x4*)(xp + q1 * XROW);
        r1 += *(const f32x4*)(xp + q1 * XROW + 4);
        r2 += *(const f32x4*)(xp + q1 * XROW + 8);
      }
      const float R[11] = {r0[0], r0[1], r0[2], r0[3], r1[0], r1[1],
                           r1[2], r1[3], r2[0], r2[1], r2[2]};
      f32x4 k0 = *(const f32x4*)(kp + d * 16);
      f32x4 k1 = *(const f32x4*)(kp + d * 16 + 4);
      f32x4 k2 = *(const f32x4*)(kp + d * 16 + 8);
      const float K[11] = {k0[0], k0[1], k0[2], k0[3], k1[0], k1[1],
                           k1[2], k1[3], k2[0], k2[1], k2[2]};
#pragma unroll
      for (int qw = 0; qw < 11; qw++) {
#pragma unroll
        for (int pw = 0; pw < 11; pw++) {
          int ki = pw - qw; if (ki < 0) ki += 11;  // compile-time
          accv[pw] = fmaf(R[qw], K[ki], accv[pw]);
        }
      }
    }
#pragma unroll
    for (int pw = 0; pw < 11; pw++)
      lo[(ph * 11 + pw) * FC + pl] = f2bf(accv[pw]);
  }
  __syncthreads();

  // cooperative coalesced write: 121 rows x 32 bf16 = 1936 dwords
  const unsigned int* lou = (const unsigned int*)lo;
#pragma unroll
  for (int i = 0; i < 6; i++) {
    int idx = tid + i * 384;
    if (idx < 1936) {
      int p = idx >> 4;
      int j = idx & 15;
      ((unsigned int*)(xf + (size_t)(b * HW + p) * C_DIM + c0))[j] = lou[idx];
    }
  }
}

// ---------------------------------------------------------------------------
// Pass 3: GEMM D[o][n] = sum_c Wb[o][c] * xf[n][c]   (identical to R3)
// BM=BN=128, BK=64, 256 thr, global_load_lds(16B), mfma_f32_16x16x32_bf16,
// 32 barrier iters, L2 swizzle (16m x 11n groups).
// Epilogue: out[b][o][p] = x[b][o][p] + g*relu(acc*alpha[o] + beta2[o]).
// ---------------------------------------------------------------------------
__global__ __launch_bounds__(256) void gemm_kernel(
    const unsigned short* __restrict__ Wb, const unsigned short* __restrict__ xf,
    const float* __restrict__ xres, const float* __restrict__ alpha,
    const float* __restrict__ beta2, const float* __restrict__ gate,
    float* __restrict__ out) {
  __shared__ __align__(16) unsigned short lds[16384];
  const int tid = threadIdx.x;
  const int wid = tid >> 6;
  const int lane = tid & 63;

  const int lid = blockIdx.y * 121 + blockIdx.x;
  const int grp = lid / 176;
  const int rem = lid - grp * 176;
  const int m0 = (rem & 15) << 7;
  const int n0 = (grp * 11 + (rem >> 4)) << 7;

  const int wm = (wid >> 1) << 6;
  const int wn = (wid & 1) << 6;

  f32x4 acc[4][4];
#pragma unroll
  for (int i = 0; i < 4; i++)
#pragma unroll
    for (int j = 0; j < 4; j++) acc[i][j] = f32x4{0.f, 0.f, 0.f, 0.f};

  const int rowlo = (wid << 4) + (lane >> 2);
  const int seg = lane & 3;
  const unsigned short* gA0 = Wb + (size_t)(m0 + rowlo) * C_DIM + seg * 8;
  const unsigned short* gA1 = gA0 + 64 * C_DIM;
  const unsigned short* gB0 = xf + (size_t)(n0 + rowlo) * C_DIM + seg * 8;
  const unsigned short* gB1 = gB0 + 64 * C_DIM;
  char* lA0 = (char*)lds + (wid << 10) + (lane << 4);
  char* lA1 = lA0 + 4096;

  const int fr = lane & 15;
  const int quad = lane >> 4;
  const unsigned short* pa = lds + ((wm + fr) << 5) + (quad << 3);
  const unsigned short* pb = lds + 8192 + ((wn + fr) << 5) + (quad << 3);

  for (int kk = 0; kk < 32; kk++) {
    gload_lds16(gA0,       lA0);
    gload_lds16(gA1,       lA1);
    gload_lds16(gA0 + 32,  lA0 + 8192);
    gload_lds16(gA1 + 32,  lA1 + 8192);
    gload_lds16(gB0,       lA0 + 16384);
    gload_lds16(gB1,       lA1 + 16384);
    gload_lds16(gB0 + 32,  lA0 + 24576);
    gload_lds16(gB1 + 32,  lA1 + 24576);
    gA0 += 64; gA1 += 64; gB0 += 64; gB1 += 64;
    asm volatile("s_waitcnt vmcnt(0)" ::: "memory");
    __syncthreads();
#pragma unroll
    for (int ks = 0; ks < 2; ks++) {
      bfrag a[4], b[4];
#pragma unroll
      for (int i = 0; i < 4; i++) {
        a[i] = *(const bfrag*)(pa + (ks << 12) + (i << 9));
        b[i] = *(const bfrag*)(pb + (ks << 12) + (i << 9));
      }
#pragma unroll
      for (int i = 0; i < 4; i++)
#pragma unroll
        for (int j = 0; j < 4; j++)
          acc[i][j] = __builtin_amdgcn_mfma_f32_16x16x32_bf16(a[i], b[j], acc[i][j], 0, 0, 0);
    }
    __syncthreads();
  }

  float g = gate[0];
  g = fminf(fmaxf(g, 0.0f), 1.0f);
  int nbase[4];
#pragma unroll
  for (int j = 0; j < 4; j++) {
    int n = n0 + wn + (j << 4) + fr;
    int bb = n / 121;
    int p = n - bb * 121;
    nbase[j] = bb * (C_DIM * HW) + p;
  }
#pragma unroll
  for (int i = 0; i < 4; i++) {
    const int ob = m0 + wm + (i << 4) + (quad << 2);
    float al[4], bt[4];
#pragma unroll
    for (int r = 0; r < 4; r++) { al[r] = alpha[ob + r]; bt[r] = beta2[ob + r]; }
#pragma unroll
    for (int j = 0; j < 4; j++) {
#pragma unroll
      for (int r = 0; r < 4; r++) {
        int addr = nbase[j] + (ob + r) * HW;
        float v = acc[i][j][r] * al[r] + bt[r];
        v = fmaxf(v, 0.0f);
        out[addr] = xres[addr] + g * v;
      }
    }
  }
}

// ---------------------------------------------------------------------------
// Workspace layout (~76 MB):
//   [0x000000, +1441792)  kws: 2048 x 176 fp32 spatial kernels (row pad 16)
//   [0x200000, +8192)     alpha
//   [0x202000, +8192)     beta2
//   [0x300000, +8388608)  Wb bf16 [2048][2048]
//   [0xC00000, +63438848) xf bf16 [15488][2048]
// ---------------------------------------------------------------------------
extern "C" void kernel_launch(void* const* d_in, const int* in_sizes, int n_in,
                              void* d_out, int out_size, void* d_ws, size_t ws_size,
                              hipStream_t stream) {
  const float* x     = (const float*)d_in[0];
  const float* ft    = (const float*)d_in[1];
  const float* gate  = (const float*)d_in[2];
  const float* W     = (const float*)d_in[3];
  const float* convb = (const float*)d_in[4];
  const float* gamma = (const float*)d_in[5];
  const float* beta  = (const float*)d_in[6];
  const float* mean  = (const float*)d_in[7];
  const float* var   = (const float*)d_in[8];
  float* out = (float*)d_out;

  char* ws = (char*)d_ws;
  float* kws            = (float*)(ws);
  float* alpha          = (float*)(ws + 0x200000);
  float* beta2          = (float*)(ws + 0x202000);
  unsigned short* Wb    = (unsigned short*)(ws + 0x300000);
  unsigned short* xf    = (unsigned short*)(ws + 0xC00000);

  prep_kernel<<<2048, 256, 0, stream>>>(ft, convb, gamma, beta, mean, var,
                                        W, Wb, kws, alpha, beta2);
  filter_kernel<<<dim3(NB, C_DIM / FC), 384, 0, stream>>>(x, kws, xf);
  gemm_kernel<<<dim3(NTOT / 128, C_DIM / 128), 256, 0, stream>>>(
      Wb, xf, x, alpha, beta2, gate, out);
}